// Round 6
// baseline (432.134 us; speedup 1.0000x reference)
//
#include <hip/hip_runtime.h>
#include <hip/hip_bf16.h>
#include <stdint.h>

#define NEG_INF (-__builtin_inff())

typedef unsigned short u16;
typedef __bf16 bf16_t;
typedef __attribute__((ext_vector_type(8))) __bf16 bf16x8;
typedef __attribute__((ext_vector_type(4))) float f32x4;
typedef __attribute__((ext_vector_type(16))) float f32x16;
typedef __attribute__((ext_vector_type(4))) u16 u16x4;
typedef __attribute__((ext_vector_type(4))) unsigned int u32x4;

typedef __attribute__((address_space(3))) void lds_void;
typedef const __attribute__((address_space(1))) void gbl_void;

__device__ __forceinline__ void gll16(const void* g, void* l) {
  __builtin_amdgcn_global_load_lds((gbl_void*)g, (lds_void*)l, 16, 0, 0);
}

__device__ __forceinline__ u16 bf16bits(float x) {
  bf16_t h = (bf16_t)x;
  return __builtin_bit_cast(u16, h);
}

// 2^x. Prefer the compiler-visible builtin (schedulable, hazard-managed); asm fallback.
#if __has_builtin(__builtin_amdgcn_exp2f)
__device__ __forceinline__ float exp2_fast(float x) { return __builtin_amdgcn_exp2f(x); }
#else
__device__ __forceinline__ float exp2_fast(float x) {
  float r;
  asm("v_exp_f32 %0, %1\n\ts_nop 0" : "=v"(r) : "v"(x));
  return r;
}
#endif

__device__ __forceinline__ f32x16 zero16() {
  f32x16 z;
#pragma unroll
  for (int i = 0; i < 16; ++i) z[i] = 0.f;
  return z;
}

#define LOG2E 1.44269504088896340736f

// ---------------- fp32 -> bf16 elementwise (both inputs, one launch) ----------------
__global__ __launch_bounds__(256) void cvt2_kernel(const float* __restrict__ qin,
                                                   const float* __restrict__ kin,
                                                   u16* __restrict__ qo, u16* __restrict__ ko) {
  int i = blockIdx.x * 256 + threadIdx.x;
  const float* src; u16* dst; int idx;
  if (i < 1048576) { src = qin; dst = qo; idx = i; }
  else { src = kin; dst = ko; idx = i - 1048576; }
  float4 v = reinterpret_cast<const float4*>(src)[idx];
  u16x4 pk;
  pk.x = bf16bits(v.x); pk.y = bf16bits(v.y);
  pk.z = bf16bits(v.z); pk.w = bf16bits(v.w);
  reinterpret_cast<u16x4*>(dst)[idx] = pk;
}

// ---------------- weight transposes, one launch (z selects) ----------------
__global__ __launch_bounds__(256) void transpose4_kernel(
    const float* __restrict__ Wq, const float* __restrict__ Wk,
    const float* __restrict__ Wv, const float* __restrict__ Wo,
    u16* __restrict__ wqT, u16* __restrict__ wkvT, u16* __restrict__ woT) {
  __shared__ float tile[64][65];
  const int z = blockIdx.z;
  const float* W = (z == 0) ? Wq : (z == 1) ? Wk : (z == 2) ? Wv : Wo;
  u16* D = (z == 0) ? wqT : (z == 1) ? wkvT : (z == 2) ? (wkvT + (size_t)1024 * 1024) : woT;
  int c0 = blockIdx.x * 64, r0 = blockIdx.y * 64;
  int tid = threadIdx.x;
#pragma unroll
  for (int i = 0; i < 16; ++i) {
    int idx = tid + i * 256;
    int r = idx >> 6, c = idx & 63;
    tile[r][c] = W[(size_t)(r0 + r) * 1024 + c0 + c];
  }
  __syncthreads();
#pragma unroll
  for (int i = 0; i < 16; ++i) {
    int idx = tid + i * 256;
    int rr = idx >> 6, cc = idx & 63;
    D[(size_t)(c0 + rr) * 1024 + r0 + cc] = bf16bits(tile[cc][rr]);
  }
}

// ---------------- fused QKV projection GEMM ----------------
// 1280 blocks of 128x128x1024: bid<256 -> Q tiles; else -> K|V tiles.
__global__ __launch_bounds__(256) void qkv_gemm_kernel(
    const u16* __restrict__ qbf, const u16* __restrict__ kbf,
    const u16* __restrict__ wqT, const u16* __restrict__ wkvT,
    const float* __restrict__ bq_, const float* __restrict__ bk_, const float* __restrict__ bv_,
    u16* __restrict__ Qb, u16* __restrict__ Kb, u16* __restrict__ Vtb) {
  __shared__ u16 As[128 * 32];
  __shared__ u16 Bs[128 * 32];
  const int tid = threadIdx.x;
  const int lane = tid & 63;
  const int wv = tid >> 6;
  const int bid = blockIdx.x;
  const bool isQ = bid < 256;
  const u16* A; const u16* Bt; int m0, n0;
  if (isQ) { A = qbf; Bt = wqT; m0 = (bid >> 3) * 128; n0 = (bid & 7) * 128; }
  else { int b2 = bid - 256; A = kbf; Bt = wkvT; m0 = (b2 >> 4) * 128; n0 = (b2 & 15) * 128; }
  const int fr = lane & 15;
  const int fg = lane >> 4;
  const int wm = (wv & 1) * 64;
  const int wn = (wv >> 1) * 64;
  const int sr = lane >> 2;
  const int sg = lane & 3;

  f32x4 zero4 = {0.f, 0.f, 0.f, 0.f};
  f32x4 acc[4][4];
#pragma unroll
  for (int i = 0; i < 4; ++i)
#pragma unroll
    for (int j = 0; j < 4; ++j) acc[i][j] = zero4;

  for (int kt = 0; kt < 1024; kt += 32) {
#pragma unroll
    for (int is = 0; is < 2; ++is) {
      int chunk = wv * 2 + is;
      int row = chunk * 16 + sr;
      int srcg = sg ^ ((row >> 1) & 3);
      gll16(A + (size_t)(m0 + row) * 1024 + kt + srcg * 8, (char*)As + chunk * 1024);
      gll16(Bt + (size_t)(n0 + row) * 1024 + kt + srcg * 8, (char*)Bs + chunk * 1024);
    }
    __syncthreads();
    bf16x8 af[4], bfr[4];
#pragma unroll
    for (int mi = 0; mi < 4; ++mi) {
      int row = wm + mi * 16 + fr;
      af[mi] = *reinterpret_cast<const bf16x8*>(
          (const char*)As + row * 64 + ((fg ^ ((row >> 1) & 3)) << 4));
    }
#pragma unroll
    for (int ni = 0; ni < 4; ++ni) {
      int row = wn + ni * 16 + fr;
      bfr[ni] = *reinterpret_cast<const bf16x8*>(
          (const char*)Bs + row * 64 + ((fg ^ ((row >> 1) & 3)) << 4));
    }
#pragma unroll
    for (int mi = 0; mi < 4; ++mi)
#pragma unroll
      for (int ni = 0; ni < 4; ++ni)
        acc[mi][ni] = __builtin_amdgcn_mfma_f32_16x16x32_bf16(af[mi], bfr[ni], acc[mi][ni], 0, 0, 0);
    __syncthreads();
  }

#pragma unroll
  for (int mi = 0; mi < 4; ++mi) {
#pragma unroll
    for (int ni = 0; ni < 4; ++ni) {
      int rbase = m0 + wm + mi * 16 + fg * 4;
      int col = n0 + wn + ni * 16 + fr;
      f32x4 v = acc[mi][ni];
      if (isQ) {
        float bs = bq_[col];
        int head = col >> 6, hd = col & 63;
        int b_ = rbase >> 11, r = rbase & 2047;
#pragma unroll
        for (int j = 0; j < 4; ++j)
          Qb[((size_t)(b_ * 16 + head) * 2048 + r + j) * 64 + hd] =
              bf16bits((v[j] + bs) * (0.125f * LOG2E));
      } else {
        int b_ = rbase >> 12, r = rbase & 4095;
        if (col < 1024) {
          float bs = bk_[col];
          int head = col >> 6, hd = col & 63;
#pragma unroll
          for (int j = 0; j < 4; ++j)
            Kb[((size_t)(b_ * 16 + head) * 4096 + r + j) * 64 + hd] = bf16bits(v[j] + bs);
        } else {
          int c = col - 1024;
          float bs = bv_[c];
          int head = c >> 6, hd = c & 63;
          u16x4 pk;
#pragma unroll
          for (int j = 0; j < 4; ++j) pk[j] = bf16bits(v[j] + bs);
          *reinterpret_cast<u16x4*>(Vtb + ((size_t)(b_ * 16 + head) * 64 + hd) * 4096 + r) = pk;
        }
      }
    }
  }
}

// ---------------- O-projection GEMM (fp32 out, 128x64 tile) ----------------
__global__ __launch_bounds__(256) void o_gemm_kernel(
    const u16* __restrict__ A, const u16* __restrict__ Bt,
    const float* __restrict__ bias, float* __restrict__ outp) {
  __shared__ u16 As[128 * 32];
  __shared__ u16 Bs[64 * 32];
  const int tid = threadIdx.x;
  const int lane = tid & 63;
  const int wv = tid >> 6;
  const int m0 = blockIdx.y * 128;
  const int n0 = blockIdx.x * 64;
  const int fr = lane & 15;
  const int fg = lane >> 4;
  const int wm = (wv & 1) * 64;
  const int wn = (wv >> 1) * 32;
  const int sr = lane >> 2;
  const int sg = lane & 3;

  f32x4 zero4 = {0.f, 0.f, 0.f, 0.f};
  f32x4 acc[4][2];
#pragma unroll
  for (int i = 0; i < 4; ++i) { acc[i][0] = zero4; acc[i][1] = zero4; }

  for (int kt = 0; kt < 1024; kt += 32) {
#pragma unroll
    for (int is = 0; is < 2; ++is) {
      int chunk = wv * 2 + is;
      int row = chunk * 16 + sr;
      int srcg = sg ^ ((row >> 1) & 3);
      gll16(A + (size_t)(m0 + row) * 1024 + kt + srcg * 8, (char*)As + chunk * 1024);
    }
    {
      int chunk = wv;
      int row = chunk * 16 + sr;
      int srcg = sg ^ ((row >> 1) & 3);
      gll16(Bt + (size_t)(n0 + row) * 1024 + kt + srcg * 8, (char*)Bs + chunk * 1024);
    }
    __syncthreads();
    bf16x8 af[4], bfr[2];
#pragma unroll
    for (int mi = 0; mi < 4; ++mi) {
      int row = wm + mi * 16 + fr;
      af[mi] = *reinterpret_cast<const bf16x8*>(
          (const char*)As + row * 64 + ((fg ^ ((row >> 1) & 3)) << 4));
    }
#pragma unroll
    for (int ni = 0; ni < 2; ++ni) {
      int row = wn + ni * 16 + fr;
      bfr[ni] = *reinterpret_cast<const bf16x8*>(
          (const char*)Bs + row * 64 + ((fg ^ ((row >> 1) & 3)) << 4));
    }
#pragma unroll
    for (int mi = 0; mi < 4; ++mi)
#pragma unroll
      for (int ni = 0; ni < 2; ++ni)
        acc[mi][ni] = __builtin_amdgcn_mfma_f32_16x16x32_bf16(af[mi], bfr[ni], acc[mi][ni], 0, 0, 0);
    __syncthreads();
  }

#pragma unroll
  for (int mi = 0; mi < 4; ++mi) {
#pragma unroll
    for (int ni = 0; ni < 2; ++ni) {
      int rbase = m0 + wm + mi * 16 + fg * 4;
      int col = n0 + wn + ni * 16 + fr;
      float bs = bias[col];
      f32x4 v = acc[mi][ni];
#pragma unroll
      for (int j = 0; j < 4; ++j) outp[(size_t)(rbase + j) * 1024 + col] = v[j] + bs;
    }
  }
}

// ---------------- flash attention: fixed-max (m=0) softmax, l via MFMA, KV-split x2 ----
// Q: (B*16, 2048, 64) pre-scaled by SCALE*log2e; K: (B*16, 4096, 64); Vt: (B*16, 64, 4096)
// blockIdx.z selects kv half; partials: pctx_z bf16 (unnormalized acc), pl[z] f32 denominators.
// __launch_bounds__(256,5): cap VGPR at ~102 for 5 waves/SIMD (R3 VGPR=56 showed 35% occ;
// R4/R5 VGPR>=100 stuck at 20% -> registers gate residency).
__global__ __launch_bounds__(256, 5) void attn_kernel(
    const u16* __restrict__ Qm, const u16* __restrict__ Km, const u16* __restrict__ Vm,
    const int* __restrict__ ansp, const int* __restrict__ qmask,
    u16* __restrict__ pctx0, u16* __restrict__ pctx1, float* __restrict__ pl) {
  __shared__ u16 Ks[2][64 * 64];
  __shared__ u16 Vs[2][64 * 64];
  const int tid = threadIdx.x;
  const int lane = tid & 63;
  const int wv = tid >> 6;
  const int bh = blockIdx.x;
  const int qt = blockIdx.y;
  const int z = blockIdx.z;
  const int b_ = bh >> 4;
  const int head = bh & 15;
  const int l31 = lane & 31;
  const int h = lane >> 5;
  const int ans = ansp[0];
  const int kt0 = (ans > 0) ? (ans & ~63) : 0;
  const int nt = (4096 - kt0) >> 6;
  const int tb = z ? (nt >> 1) : 0;
  const int te = z ? nt : (nt >> 1);

  const u16* Kg = Km + (size_t)bh * 4096 * 64;
  const u16* Vg = Vm + (size_t)bh * 64 * 4096;
  const int q = qt * 128 + wv * 32 + l31;

  // Q fragments in registers: bq[s] = Q[q][s*16 + 8h .. +7]
  bf16x8 bq[4];
  {
    const u16* Qrow = Qm + ((size_t)bh * 2048 + q) * 64;
#pragma unroll
    for (int s = 0; s < 4; ++s)
      bq[s] = *reinterpret_cast<const bf16x8*>(Qrow + s * 16 + h * 8);
  }

  float qmv = (qmask[b_ * 2048 + q] == 0) ? NEG_INF : 0.f;
  const bool anyq = __ballot(qmv != 0.f) != 0ull;

  // all-ones A fragment for the denominator MFMA
  const u32x4 onesw = {0x3F803F80u, 0x3F803F80u, 0x3F803F80u, 0x3F803F80u};
  const bf16x8 ones = __builtin_bit_cast(bf16x8, onesw);

  // per-lane LDS byte offsets (same pattern for K rows and V^T rows)
  int offs[2][4];
#pragma unroll
  for (int t = 0; t < 2; ++t)
#pragma unroll
    for (int s = 0; s < 4; ++s) {
      int row = t * 32 + l31;
      offs[t][s] = row * 128 + ((((s << 1) | h) ^ (row & 7)) << 4);
    }

  const int sr8 = lane >> 3;
  const int sg8 = lane & 7;

  f32x16 acc[2], accl;
  acc[0] = zero16(); acc[1] = zero16(); accl = zero16();

  // prologue stage
  if (tb < te) {
    int ktp = kt0 + tb * 64;
#pragma unroll
    for (int is = 0; is < 2; ++is) {
      int chunk = wv * 2 + is;
      int row = chunk * 8 + sr8;
      int srcg = sg8 ^ (row & 7);
      gll16(Kg + (size_t)(ktp + row) * 64 + srcg * 8, (char*)&Ks[0][0] + chunk * 1024);
      gll16(Vg + (size_t)row * 4096 + ktp + srcg * 8, (char*)&Vs[0][0] + chunk * 1024);
    }
  }
  __syncthreads();

  int cur = 0;
  for (int t = tb; t < te; ++t) {
    const int kt = kt0 + t * 64;
    // stage next tile into other buffer (overlaps with compute below)
    if (t + 1 < te) {
#pragma unroll
      for (int is = 0; is < 2; ++is) {
        int chunk = wv * 2 + is;
        int row = chunk * 8 + sr8;
        int srcg = sg8 ^ (row & 7);
        gll16(Kg + (size_t)(kt + 64 + row) * 64 + srcg * 8, (char*)&Ks[cur ^ 1][0] + chunk * 1024);
        gll16(Vg + (size_t)row * 4096 + kt + 64 + srcg * 8, (char*)&Vs[cur ^ 1][0] + chunk * 1024);
      }
    }
    const char* kb = (const char*)&Ks[cur][0];
    const char* vb = (const char*)&Vs[cur][0];

    // S^T = K * Q^T : two 32-kv subtiles, cols = wave's 32 q
    f32x16 st[2];
    st[0] = zero16(); st[1] = zero16();
    __builtin_amdgcn_s_setprio(1);
#pragma unroll
    for (int t2 = 0; t2 < 2; ++t2)
#pragma unroll
      for (int s = 0; s < 4; ++s) {
        bf16x8 ak = *reinterpret_cast<const bf16x8*>(kb + offs[t2][s]);
        st[t2] = __builtin_amdgcn_mfma_f32_32x32x16_bf16(ak, bq[s], st[t2], 0, 0, 0);
      }
    __builtin_amdgcn_s_setprio(0);

    // masks (wave-uniform branches, taken on at most one tile / all-ones qmask)
    if (kt < ans) {
#pragma unroll
      for (int t2 = 0; t2 < 2; ++t2)
#pragma unroll
        for (int r = 0; r < 16; ++r) {
          int kv = kt + t2 * 32 + (r & 3) + 8 * (r >> 2) + 4 * h;
          if (kv < ans) st[t2][r] = NEG_INF;
        }
    }
    if (anyq) {
#pragma unroll
      for (int t2 = 0; t2 < 2; ++t2)
#pragma unroll
        for (int r = 0; r < 16; ++r) st[t2][r] += qmv;
    }

    // fixed-max softmax: p = 2^s directly; pack to bf16 pairs
    unsigned pk[16];
#pragma unroll
    for (int t2 = 0; t2 < 2; ++t2)
#pragma unroll
      for (int r = 0; r < 8; ++r) {
        float pa = exp2_fast(st[t2][2 * r]);
        float pb = exp2_fast(st[t2][2 * r + 1]);
        asm("v_cvt_pk_bf16_f32 %0, %1, %2" : "=v"(pk[t2 * 8 + r]) : "v"(pa), "v"(pb));
      }
#pragma unroll
    for (int t2 = 0; t2 < 2; ++t2) {
      asm("v_permlane32_swap_b32 %0, %1" : "+v"(pk[t2 * 8 + 0]), "+v"(pk[t2 * 8 + 2]));
      asm("v_permlane32_swap_b32 %0, %1" : "+v"(pk[t2 * 8 + 1]), "+v"(pk[t2 * 8 + 3]));
      asm("v_permlane32_swap_b32 %0, %1" : "+v"(pk[t2 * 8 + 4]), "+v"(pk[t2 * 8 + 6]));
      asm("v_permlane32_swap_b32 %0, %1" : "+v"(pk[t2 * 8 + 5]), "+v"(pk[t2 * 8 + 7]));
    }
    bf16x8 bp[4];
#pragma unroll
    for (int ks = 0; ks < 4; ++ks) {
      u32x4 w = {pk[ks * 4 + 0], pk[ks * 4 + 1], pk[ks * 4 + 2], pk[ks * 4 + 3]};
      bp[ks] = __builtin_bit_cast(bf16x8, w);
    }

    // ctx^T += V^T * P^T ; denominator accumulates on the MFMA pipe (A = ones)
    __builtin_amdgcn_s_setprio(1);
#pragma unroll
    for (int ht = 0; ht < 2; ++ht)
#pragma unroll
      for (int ks = 0; ks < 4; ++ks) {
        bf16x8 av = *reinterpret_cast<const bf16x8*>(vb + offs[ht][ks]);
        acc[ht] = __builtin_amdgcn_mfma_f32_32x32x16_bf16(av, bp[ks], acc[ht], 0, 0, 0);
      }
#pragma unroll
    for (int ks = 0; ks < 4; ++ks)
      accl = __builtin_amdgcn_mfma_f32_32x32x16_bf16(ones, bp[ks], accl, 0, 0, 0);
    __builtin_amdgcn_s_setprio(0);

    __syncthreads();  // drains vmcnt: next buffer staged; all waves done with cur
    cur ^= 1;
  }

  // write unnormalized partial ctx + denominator
  {
    u16* pc = z ? pctx1 : pctx0;
    u16* cbase = pc + ((size_t)b_ * 2048 + q) * 1024 + head * 64;
#pragma unroll
    for (int ht = 0; ht < 2; ++ht)
#pragma unroll
      for (int rg = 0; rg < 4; ++rg) {
        u16x4 o;
#pragma unroll
        for (int j = 0; j < 4; ++j) o[j] = bf16bits(acc[ht][rg * 4 + j]);
        *reinterpret_cast<u16x4*>(cbase + ht * 32 + rg * 8 + 4 * h) = o;
      }
    if (h == 0) pl[(size_t)z * 32768 + (size_t)bh * 2048 + q] = accl[0];
  }
}

// ---------------- merge partials: ctx = (a0+a1)/(l0+l1) ----------------
__global__ __launch_bounds__(256) void merge_kernel(
    const u16* __restrict__ p0, const u16* __restrict__ p1,
    const float* __restrict__ pl, u16* __restrict__ ctxm) {
  const int row = blockIdx.x;      // b*2048 + q
  const int t = threadIdx.x;       // 4 elems each
  const int col = t * 4;
  const int head = col >> 6;
  const int b = row >> 11, q = row & 2047;
  const int li = (b * 16 + head) * 2048 + q;
  const float inv = 1.f / (pl[li] + pl[32768 + li]);
  u16x4 a = reinterpret_cast<const u16x4*>(p0 + (size_t)row * 1024)[t];
  u16x4 c = reinterpret_cast<const u16x4*>(p1 + (size_t)row * 1024)[t];
  u16x4 o;
#pragma unroll
  for (int j = 0; j < 4; ++j) {
    float fa = __builtin_bit_cast(float, (unsigned)((unsigned)a[j] << 16));
    float fc = __builtin_bit_cast(float, (unsigned)((unsigned)c[j] << 16));
    o[j] = bf16bits((fa + fc) * inv);
  }
  reinterpret_cast<u16x4*>(ctxm + (size_t)row * 1024)[t] = o;
}

// ---------------- residual + LayerNorm ----------------
__global__ __launch_bounds__(256) void ln_kernel(
    const float* __restrict__ oproj, const float* __restrict__ qv,
    const float* __restrict__ lw, const float* __restrict__ lb,
    float* __restrict__ out) {
  const int row = blockIdx.x;
  const int tid = threadIdx.x;
  const int lane = tid & 63;
  const int wv = tid >> 6;
  const float4 o4 = reinterpret_cast<const float4*>(oproj + (size_t)row * 1024)[tid];
  const float4 q4 = reinterpret_cast<const float4*>(qv + (size_t)row * 1024)[tid];
  float x0 = o4.x + q4.x, x1 = o4.y + q4.y, x2 = o4.z + q4.z, x3 = o4.w + q4.w;
  float s = x0 + x1 + x2 + x3;
  float s2 = x0 * x0 + x1 * x1 + x2 * x2 + x3 * x3;
#pragma unroll
  for (int d = 1; d < 64; d <<= 1) { s += __shfl_xor(s, d); s2 += __shfl_xor(s2, d); }
  __shared__ float red[8];
  if (lane == 0) { red[wv] = s; red[4 + wv] = s2; }
  __syncthreads();
  s = red[0] + red[1] + red[2] + red[3];
  s2 = red[4] + red[5] + red[6] + red[7];
  const float mu = s * (1.f / 1024.f);
  const float var = s2 * (1.f / 1024.f) - mu * mu;
  const float rs = rsqrtf(var + 1e-5f);
  const float4 w4 = reinterpret_cast<const float4*>(lw)[tid];
  const float4 b4 = reinterpret_cast<const float4*>(lb)[tid];
  float4 r;
  r.x = (x0 - mu) * rs * w4.x + b4.x;
  r.y = (x1 - mu) * rs * w4.y + b4.y;
  r.z = (x2 - mu) * rs * w4.z + b4.z;
  r.w = (x3 - mu) * rs * w4.w + b4.w;
  reinterpret_cast<float4*>(out + (size_t)row * 1024)[tid] = r;
}

extern "C" void kernel_launch(void* const* d_in, const int* in_sizes, int n_in,
                              void* d_out, int out_size, void* d_ws, size_t ws_size,
                              hipStream_t stream) {
  const float* qv = (const float*)d_in[0];
  const float* kn = (const float*)d_in[1];
  const int* amask = (const int*)d_in[2];
  const int* ansp = (const int*)d_in[3];
  const float* Wq = (const float*)d_in[4];
  const float* bq = (const float*)d_in[5];
  const float* Wk = (const float*)d_in[6];
  const float* bk = (const float*)d_in[7];
  const float* Wv = (const float*)d_in[8];
  const float* bv = (const float*)d_in[9];
  const float* Wo = (const float*)d_in[10];
  const float* bo = (const float*)d_in[11];
  const float* lnw = (const float*)d_in[12];
  const float* lnb = (const float*)d_in[13];

  char* ws = (char*)d_ws;
  u16* qbf  = (u16*)(ws);
  u16* kbf  = (u16*)(ws + (size_t)(8u << 20));
  u16* pctx0 = qbf;
  u16* pctx1 = kbf;
  float* pl = (float*)(ws + (size_t)(16u << 20));
  u16* ctxm = (u16*)(ws + (size_t)(17u << 20));
  u16* wqT  = (u16*)(ws + (size_t)(24u << 20));
  u16* wkvT = (u16*)(ws + (size_t)(26u << 20));
  u16* woT  = (u16*)(ws + (size_t)(30u << 20));
  u16* Qb   = (u16*)(ws + (size_t)(32u << 20));
  u16* Kb   = (u16*)(ws + (size_t)(40u << 20));
  u16* Vtb  = (u16*)(ws + (size_t)(56u << 20));
  float* oproj = (float*)(ws + (size_t)(32u << 20));

  cvt2_kernel<<<12288, 256, 0, stream>>>(qv, kn, qbf, kbf);
  transpose4_kernel<<<dim3(16, 16, 4), 256, 0, stream>>>(Wq, Wk, Wv, Wo, wqT, wkvT, woT);
  qkv_gemm_kernel<<<1280, 256, 0, stream>>>(qbf, kbf, wqT, wkvT, bq, bk, bv, Qb, Kb, Vtb);
  attn_kernel<<<dim3(32, 16, 2), 256, 0, stream>>>(Qb, Kb, Vtb, ansp, amask, pctx0, pctx1, pl);
  merge_kernel<<<4096, 256, 0, stream>>>(pctx0, pctx1, pl, ctxm);
  o_gemm_kernel<<<dim3(16, 32), 256, 0, stream>>>(ctxm, woT, bo, oproj);
  ln_kernel<<<4096, 256, 0, stream>>>(oproj, qv, lnw, lnb, (float*)d_out);
}

// Round 8
// 314.126 us; speedup vs baseline: 1.3757x; 1.3757x over previous
//
#include <hip/hip_runtime.h>
#include <hip/hip_bf16.h>
#include <stdint.h>

#define NEG_INF (-__builtin_inff())

typedef unsigned short u16;
typedef __bf16 bf16_t;
typedef __attribute__((ext_vector_type(8))) __bf16 bf16x8;
typedef __attribute__((ext_vector_type(4))) float f32x4;
typedef __attribute__((ext_vector_type(16))) float f32x16;
typedef __attribute__((ext_vector_type(4))) u16 u16x4;
typedef __attribute__((ext_vector_type(4))) unsigned int u32x4;

typedef __attribute__((address_space(3))) void lds_void;
typedef const __attribute__((address_space(1))) void gbl_void;

__device__ __forceinline__ void gll16(const void* g, void* l) {
  __builtin_amdgcn_global_load_lds((gbl_void*)g, (lds_void*)l, 16, 0, 0);
}

__device__ __forceinline__ u16 bf16bits(float x) {
  bf16_t h = (bf16_t)x;
  return __builtin_bit_cast(u16, h);
}

// 2^x. Prefer the compiler-visible builtin (schedulable, hazard-managed); asm fallback.
#if __has_builtin(__builtin_amdgcn_exp2f)
__device__ __forceinline__ float exp2_fast(float x) { return __builtin_amdgcn_exp2f(x); }
#else
__device__ __forceinline__ float exp2_fast(float x) {
  float r;
  asm("v_exp_f32 %0, %1\n\ts_nop 0" : "=v"(r) : "v"(x));
  return r;
}
#endif

__device__ __forceinline__ f32x16 zero16() {
  f32x16 z;
#pragma unroll
  for (int i = 0; i < 16; ++i) z[i] = 0.f;
  return z;
}

#define LOG2E 1.44269504088896340736f

// ---------------- fp32 -> bf16 elementwise (both inputs, one launch) ----------------
__global__ __launch_bounds__(256) void cvt2_kernel(const float* __restrict__ qin,
                                                   const float* __restrict__ kin,
                                                   u16* __restrict__ qo, u16* __restrict__ ko) {
  int i = blockIdx.x * 256 + threadIdx.x;
  const float* src; u16* dst; int idx;
  if (i < 1048576) { src = qin; dst = qo; idx = i; }
  else { src = kin; dst = ko; idx = i - 1048576; }
  float4 v = reinterpret_cast<const float4*>(src)[idx];
  u16x4 pk;
  pk.x = bf16bits(v.x); pk.y = bf16bits(v.y);
  pk.z = bf16bits(v.z); pk.w = bf16bits(v.w);
  reinterpret_cast<u16x4*>(dst)[idx] = pk;
}

// ---------------- weight transposes, one launch (z selects) ----------------
__global__ __launch_bounds__(256) void transpose4_kernel(
    const float* __restrict__ Wq, const float* __restrict__ Wk,
    const float* __restrict__ Wv, const float* __restrict__ Wo,
    u16* __restrict__ wqT, u16* __restrict__ wkvT, u16* __restrict__ woT) {
  __shared__ float tile[64][65];
  const int z = blockIdx.z;
  const float* W = (z == 0) ? Wq : (z == 1) ? Wk : (z == 2) ? Wv : Wo;
  u16* D = (z == 0) ? wqT : (z == 1) ? wkvT : (z == 2) ? (wkvT + (size_t)1024 * 1024) : woT;
  int c0 = blockIdx.x * 64, r0 = blockIdx.y * 64;
  int tid = threadIdx.x;
#pragma unroll
  for (int i = 0; i < 16; ++i) {
    int idx = tid + i * 256;
    int r = idx >> 6, c = idx & 63;
    tile[r][c] = W[(size_t)(r0 + r) * 1024 + c0 + c];
  }
  __syncthreads();
#pragma unroll
  for (int i = 0; i < 16; ++i) {
    int idx = tid + i * 256;
    int rr = idx >> 6, cc = idx & 63;
    D[(size_t)(c0 + rr) * 1024 + r0 + cc] = bf16bits(tile[cc][rr]);
  }
}

// ---------------- fused QKV projection GEMM ----------------
// 1280 blocks of 128x128x1024: bid<256 -> Q tiles; else -> K|V tiles.
__global__ __launch_bounds__(256) void qkv_gemm_kernel(
    const u16* __restrict__ qbf, const u16* __restrict__ kbf,
    const u16* __restrict__ wqT, const u16* __restrict__ wkvT,
    const float* __restrict__ bq_, const float* __restrict__ bk_, const float* __restrict__ bv_,
    u16* __restrict__ Qb, u16* __restrict__ Kb, u16* __restrict__ Vtb) {
  __shared__ u16 As[128 * 32];
  __shared__ u16 Bs[128 * 32];
  const int tid = threadIdx.x;
  const int lane = tid & 63;
  const int wv = tid >> 6;
  const int bid = blockIdx.x;
  const bool isQ = bid < 256;
  const u16* A; const u16* Bt; int m0, n0;
  if (isQ) { A = qbf; Bt = wqT; m0 = (bid >> 3) * 128; n0 = (bid & 7) * 128; }
  else { int b2 = bid - 256; A = kbf; Bt = wkvT; m0 = (b2 >> 4) * 128; n0 = (b2 & 15) * 128; }
  const int fr = lane & 15;
  const int fg = lane >> 4;
  const int wm = (wv & 1) * 64;
  const int wn = (wv >> 1) * 64;
  const int sr = lane >> 2;
  const int sg = lane & 3;

  f32x4 zero4 = {0.f, 0.f, 0.f, 0.f};
  f32x4 acc[4][4];
#pragma unroll
  for (int i = 0; i < 4; ++i)
#pragma unroll
    for (int j = 0; j < 4; ++j) acc[i][j] = zero4;

  for (int kt = 0; kt < 1024; kt += 32) {
#pragma unroll
    for (int is = 0; is < 2; ++is) {
      int chunk = wv * 2 + is;
      int row = chunk * 16 + sr;
      int srcg = sg ^ ((row >> 1) & 3);
      gll16(A + (size_t)(m0 + row) * 1024 + kt + srcg * 8, (char*)As + chunk * 1024);
      gll16(Bt + (size_t)(n0 + row) * 1024 + kt + srcg * 8, (char*)Bs + chunk * 1024);
    }
    __syncthreads();
    bf16x8 af[4], bfr[4];
#pragma unroll
    for (int mi = 0; mi < 4; ++mi) {
      int row = wm + mi * 16 + fr;
      af[mi] = *reinterpret_cast<const bf16x8*>(
          (const char*)As + row * 64 + ((fg ^ ((row >> 1) & 3)) << 4));
    }
#pragma unroll
    for (int ni = 0; ni < 4; ++ni) {
      int row = wn + ni * 16 + fr;
      bfr[ni] = *reinterpret_cast<const bf16x8*>(
          (const char*)Bs + row * 64 + ((fg ^ ((row >> 1) & 3)) << 4));
    }
#pragma unroll
    for (int mi = 0; mi < 4; ++mi)
#pragma unroll
      for (int ni = 0; ni < 4; ++ni)
        acc[mi][ni] = __builtin_amdgcn_mfma_f32_16x16x32_bf16(af[mi], bfr[ni], acc[mi][ni], 0, 0, 0);
    __syncthreads();
  }

#pragma unroll
  for (int mi = 0; mi < 4; ++mi) {
#pragma unroll
    for (int ni = 0; ni < 4; ++ni) {
      int rbase = m0 + wm + mi * 16 + fg * 4;
      int col = n0 + wn + ni * 16 + fr;
      f32x4 v = acc[mi][ni];
      if (isQ) {
        float bs = bq_[col];
        int head = col >> 6, hd = col & 63;
        int b_ = rbase >> 11, r = rbase & 2047;
#pragma unroll
        for (int j = 0; j < 4; ++j)
          Qb[((size_t)(b_ * 16 + head) * 2048 + r + j) * 64 + hd] =
              bf16bits((v[j] + bs) * (0.125f * LOG2E));
      } else {
        int b_ = rbase >> 12, r = rbase & 4095;
        if (col < 1024) {
          float bs = bk_[col];
          int head = col >> 6, hd = col & 63;
#pragma unroll
          for (int j = 0; j < 4; ++j)
            Kb[((size_t)(b_ * 16 + head) * 4096 + r + j) * 64 + hd] = bf16bits(v[j] + bs);
        } else {
          int c = col - 1024;
          float bs = bv_[c];
          int head = c >> 6, hd = c & 63;
          u16x4 pk;
#pragma unroll
          for (int j = 0; j < 4; ++j) pk[j] = bf16bits(v[j] + bs);
          *reinterpret_cast<u16x4*>(Vtb + ((size_t)(b_ * 16 + head) * 64 + hd) * 4096 + r) = pk;
        }
      }
    }
  }
}

// ---------------- O-projection GEMM (fp32 out, 128x64 tile) ----------------
__global__ __launch_bounds__(256) void o_gemm_kernel(
    const u16* __restrict__ A, const u16* __restrict__ Bt,
    const float* __restrict__ bias, float* __restrict__ outp) {
  __shared__ u16 As[128 * 32];
  __shared__ u16 Bs[64 * 32];
  const int tid = threadIdx.x;
  const int lane = tid & 63;
  const int wv = tid >> 6;
  const int m0 = blockIdx.y * 128;
  const int n0 = blockIdx.x * 64;
  const int fr = lane & 15;
  const int fg = lane >> 4;
  const int wm = (wv & 1) * 64;
  const int wn = (wv >> 1) * 32;
  const int sr = lane >> 2;
  const int sg = lane & 3;

  f32x4 zero4 = {0.f, 0.f, 0.f, 0.f};
  f32x4 acc[4][2];
#pragma unroll
  for (int i = 0; i < 4; ++i) { acc[i][0] = zero4; acc[i][1] = zero4; }

  for (int kt = 0; kt < 1024; kt += 32) {
#pragma unroll
    for (int is = 0; is < 2; ++is) {
      int chunk = wv * 2 + is;
      int row = chunk * 16 + sr;
      int srcg = sg ^ ((row >> 1) & 3);
      gll16(A + (size_t)(m0 + row) * 1024 + kt + srcg * 8, (char*)As + chunk * 1024);
    }
    {
      int chunk = wv;
      int row = chunk * 16 + sr;
      int srcg = sg ^ ((row >> 1) & 3);
      gll16(Bt + (size_t)(n0 + row) * 1024 + kt + srcg * 8, (char*)Bs + chunk * 1024);
    }
    __syncthreads();
    bf16x8 af[4], bfr[2];
#pragma unroll
    for (int mi = 0; mi < 4; ++mi) {
      int row = wm + mi * 16 + fr;
      af[mi] = *reinterpret_cast<const bf16x8*>(
          (const char*)As + row * 64 + ((fg ^ ((row >> 1) & 3)) << 4));
    }
#pragma unroll
    for (int ni = 0; ni < 2; ++ni) {
      int row = wn + ni * 16 + fr;
      bfr[ni] = *reinterpret_cast<const bf16x8*>(
          (const char*)Bs + row * 64 + ((fg ^ ((row >> 1) & 3)) << 4));
    }
#pragma unroll
    for (int mi = 0; mi < 4; ++mi)
#pragma unroll
      for (int ni = 0; ni < 2; ++ni)
        acc[mi][ni] = __builtin_amdgcn_mfma_f32_16x16x32_bf16(af[mi], bfr[ni], acc[mi][ni], 0, 0, 0);
    __syncthreads();
  }

#pragma unroll
  for (int mi = 0; mi < 4; ++mi) {
#pragma unroll
    for (int ni = 0; ni < 2; ++ni) {
      int rbase = m0 + wm + mi * 16 + fg * 4;
      int col = n0 + wn + ni * 16 + fr;
      float bs = bias[col];
      f32x4 v = acc[mi][ni];
#pragma unroll
      for (int j = 0; j < 4; ++j) outp[(size_t)(rbase + j) * 1024 + col] = v[j] + bs;
    }
  }
}

// ---------------- flash attention: fixed-max softmax, VALU lsum, KV-split x2 ----------
// Register diet vs R5: st processed one 32-kv subtile at a time (16 live, not 32);
// accl ones-MFMA removed (16 AGPRs freed) -> lane-local VALU lsum + one permlane at end.
// Live set ~110 regs -> __launch_bounds__(256,4) caps at 128 WITHOUT spilling
// (R6 lesson: (256,5)=102 cap spilled acc -> 0.5 GB scratch writes).
__global__ __launch_bounds__(256, 4) void attn_kernel(
    const u16* __restrict__ Qm, const u16* __restrict__ Km, const u16* __restrict__ Vm,
    const int* __restrict__ ansp, const int* __restrict__ qmask,
    u16* __restrict__ pctx0, u16* __restrict__ pctx1, float* __restrict__ pl) {
  __shared__ u16 Ks[2][64 * 64];
  __shared__ u16 Vs[2][64 * 64];
  const int tid = threadIdx.x;
  const int lane = tid & 63;
  const int wv = tid >> 6;
  const int bh = blockIdx.x;
  const int qt = blockIdx.y;
  const int z = blockIdx.z;
  const int b_ = bh >> 4;
  const int head = bh & 15;
  const int l31 = lane & 31;
  const int h = lane >> 5;
  const int ans = ansp[0];
  const int kt0 = (ans > 0) ? (ans & ~63) : 0;
  const int nt = (4096 - kt0) >> 6;
  const int tb = z ? (nt >> 1) : 0;
  const int te = z ? nt : (nt >> 1);

  const u16* Kg = Km + (size_t)bh * 4096 * 64;
  const u16* Vg = Vm + (size_t)bh * 64 * 4096;
  const int q = qt * 128 + wv * 32 + l31;

  // Q fragments in registers: bq[s] = Q[q][s*16 + 8h .. +7]
  bf16x8 bq[4];
  {
    const u16* Qrow = Qm + ((size_t)bh * 2048 + q) * 64;
#pragma unroll
    for (int s = 0; s < 4; ++s)
      bq[s] = *reinterpret_cast<const bf16x8*>(Qrow + s * 16 + h * 8);
  }

  float qmv = (qmask[b_ * 2048 + q] == 0) ? NEG_INF : 0.f;
  const bool anyq = __ballot(qmv != 0.f) != 0ull;

  // per-lane LDS byte offsets (same pattern for K rows and V^T rows)
  int offs[2][4];
#pragma unroll
  for (int t = 0; t < 2; ++t)
#pragma unroll
    for (int s = 0; s < 4; ++s) {
      int row = t * 32 + l31;
      offs[t][s] = row * 128 + ((((s << 1) | h) ^ (row & 7)) << 4);
    }

  const int sr8 = lane >> 3;
  const int sg8 = lane & 7;

  f32x16 acc[2];
  acc[0] = zero16(); acc[1] = zero16();
  float lrun = 0.f;

  // prologue stage
  if (tb < te) {
    int ktp = kt0 + tb * 64;
#pragma unroll
    for (int is = 0; is < 2; ++is) {
      int chunk = wv * 2 + is;
      int row = chunk * 8 + sr8;
      int srcg = sg8 ^ (row & 7);
      gll16(Kg + (size_t)(ktp + row) * 64 + srcg * 8, (char*)&Ks[0][0] + chunk * 1024);
      gll16(Vg + (size_t)row * 4096 + ktp + srcg * 8, (char*)&Vs[0][0] + chunk * 1024);
    }
  }
  __syncthreads();

  int cur = 0;
  for (int t = tb; t < te; ++t) {
    const int kt = kt0 + t * 64;
    // stage next tile into other buffer (overlaps with compute below)
    if (t + 1 < te) {
#pragma unroll
      for (int is = 0; is < 2; ++is) {
        int chunk = wv * 2 + is;
        int row = chunk * 8 + sr8;
        int srcg = sg8 ^ (row & 7);
        gll16(Kg + (size_t)(kt + 64 + row) * 64 + srcg * 8, (char*)&Ks[cur ^ 1][0] + chunk * 1024);
        gll16(Vg + (size_t)row * 4096 + kt + 64 + srcg * 8, (char*)&Vs[cur ^ 1][0] + chunk * 1024);
      }
    }
    const char* kb = (const char*)&Ks[cur][0];
    const char* vb = (const char*)&Vs[cur][0];

    // Per 32-kv subtile: QK^T -> mask -> p=2^s -> pack. st lives only inside the iteration.
    unsigned pk[16];
#pragma unroll
    for (int t2 = 0; t2 < 2; ++t2) {
      f32x16 st = zero16();
      __builtin_amdgcn_s_setprio(1);
#pragma unroll
      for (int s = 0; s < 4; ++s) {
        bf16x8 ak = *reinterpret_cast<const bf16x8*>(kb + offs[t2][s]);
        st = __builtin_amdgcn_mfma_f32_32x32x16_bf16(ak, bq[s], st, 0, 0, 0);
      }
      __builtin_amdgcn_s_setprio(0);

      if (kt < ans) {  // wave-uniform, at most one tile
#pragma unroll
        for (int r = 0; r < 16; ++r) {
          int kv = kt + t2 * 32 + (r & 3) + 8 * (r >> 2) + 4 * h;
          if (kv < ans) st[r] = NEG_INF;
        }
      }
      if (anyq) {
#pragma unroll
        for (int r = 0; r < 16; ++r) st[r] += qmv;
      }

#pragma unroll
      for (int r = 0; r < 8; ++r) {
        float pa = exp2_fast(st[2 * r]);
        float pb = exp2_fast(st[2 * r + 1]);
        lrun += pa + pb;   // lane-local denominator partial (pre-swap)
        asm("v_cvt_pk_bf16_f32 %0, %1, %2" : "=v"(pk[t2 * 8 + r]) : "v"(pa), "v"(pb));
      }
      asm("v_permlane32_swap_b32 %0, %1" : "+v"(pk[t2 * 8 + 0]), "+v"(pk[t2 * 8 + 2]));
      asm("v_permlane32_swap_b32 %0, %1" : "+v"(pk[t2 * 8 + 1]), "+v"(pk[t2 * 8 + 3]));
      asm("v_permlane32_swap_b32 %0, %1" : "+v"(pk[t2 * 8 + 4]), "+v"(pk[t2 * 8 + 6]));
      asm("v_permlane32_swap_b32 %0, %1" : "+v"(pk[t2 * 8 + 5]), "+v"(pk[t2 * 8 + 7]));
    }

    bf16x8 bp[4];
#pragma unroll
    for (int ks = 0; ks < 4; ++ks) {
      u32x4 w = {pk[ks * 4 + 0], pk[ks * 4 + 1], pk[ks * 4 + 2], pk[ks * 4 + 3]};
      bp[ks] = __builtin_bit_cast(bf16x8, w);
    }

    // ctx^T += V^T * P^T
    __builtin_amdgcn_s_setprio(1);
#pragma unroll
    for (int ht = 0; ht < 2; ++ht)
#pragma unroll
      for (int ks = 0; ks < 4; ++ks) {
        bf16x8 av = *reinterpret_cast<const bf16x8*>(vb + offs[ht][ks]);
        acc[ht] = __builtin_amdgcn_mfma_f32_32x32x16_bf16(av, bp[ks], acc[ht], 0, 0, 0);
      }
    __builtin_amdgcn_s_setprio(0);

    __syncthreads();  // drains vmcnt: next buffer staged; all waves done with cur
    cur ^= 1;
  }

  // merge the two lane-halves of the denominator: each lane covered 32 of 64 kv rows
  {
    float a = lrun, b = lrun;
    asm("v_permlane32_swap_b32 %0, %1" : "+v"(a), "+v"(b));
    lrun = a + b;
  }

  // write unnormalized partial ctx + denominator
  {
    u16* pc = z ? pctx1 : pctx0;
    u16* cbase = pc + ((size_t)b_ * 2048 + q) * 1024 + head * 64;
#pragma unroll
    for (int ht = 0; ht < 2; ++ht)
#pragma unroll
      for (int rg = 0; rg < 4; ++rg) {
        u16x4 o;
#pragma unroll
        for (int j = 0; j < 4; ++j) o[j] = bf16bits(acc[ht][rg * 4 + j]);
        *reinterpret_cast<u16x4*>(cbase + ht * 32 + rg * 8 + 4 * h) = o;
      }
    if (h == 0) pl[(size_t)z * 32768 + (size_t)bh * 2048 + q] = lrun;
  }
}

// ---------------- merge partials: ctx = (a0+a1)/(l0+l1) ----------------
__global__ __launch_bounds__(256) void merge_kernel(
    const u16* __restrict__ p0, const u16* __restrict__ p1,
    const float* __restrict__ pl, u16* __restrict__ ctxm) {
  const int row = blockIdx.x;      // b*2048 + q
  const int t = threadIdx.x;       // 4 elems each
  const int col = t * 4;
  const int head = col >> 6;
  const int b = row >> 11, q = row & 2047;
  const int li = (b * 16 + head) * 2048 + q;
  const float inv = 1.f / (pl[li] + pl[32768 + li]);
  u16x4 a = reinterpret_cast<const u16x4*>(p0 + (size_t)row * 1024)[t];
  u16x4 c = reinterpret_cast<const u16x4*>(p1 + (size_t)row * 1024)[t];
  u16x4 o;
#pragma unroll
  for (int j = 0; j < 4; ++j) {
    float fa = __builtin_bit_cast(float, (unsigned)((unsigned)a[j] << 16));
    float fc = __builtin_bit_cast(float, (unsigned)((unsigned)c[j] << 16));
    o[j] = bf16bits((fa + fc) * inv);
  }
  reinterpret_cast<u16x4*>(ctxm + (size_t)row * 1024)[t] = o;
}

// ---------------- residual + LayerNorm ----------------
__global__ __launch_bounds__(256) void ln_kernel(
    const float* __restrict__ oproj, const float* __restrict__ qv,
    const float* __restrict__ lw, const float* __restrict__ lb,
    float* __restrict__ out) {
  const int row = blockIdx.x;
  const int tid = threadIdx.x;
  const int lane = tid & 63;
  const int wv = tid >> 6;
  const float4 o4 = reinterpret_cast<const float4*>(oproj + (size_t)row * 1024)[tid];
  const float4 q4 = reinterpret_cast<const float4*>(qv + (size_t)row * 1024)[tid];
  float x0 = o4.x + q4.x, x1 = o4.y + q4.y, x2 = o4.z + q4.z, x3 = o4.w + q4.w;
  float s = x0 + x1 + x2 + x3;
  float s2 = x0 * x0 + x1 * x1 + x2 * x2 + x3 * x3;
#pragma unroll
  for (int d = 1; d < 64; d <<= 1) { s += __shfl_xor(s, d); s2 += __shfl_xor(s2, d); }
  __shared__ float red[8];
  if (lane == 0) { red[wv] = s; red[4 + wv] = s2; }
  __syncthreads();
  s = red[0] + red[1] + red[2] + red[3];
  s2 = red[4] + red[5] + red[6] + red[7];
  const float mu = s * (1.f / 1024.f);
  const float var = s2 * (1.f / 1024.f) - mu * mu;
  const float rs = rsqrtf(var + 1e-5f);
  const float4 w4 = reinterpret_cast<const float4*>(lw)[tid];
  const float4 b4 = reinterpret_cast<const float4*>(lb)[tid];
  float4 r;
  r.x = (x0 - mu) * rs * w4.x + b4.x;
  r.y = (x1 - mu) * rs * w4.y + b4.y;
  r.z = (x2 - mu) * rs * w4.z + b4.z;
  r.w = (x3 - mu) * rs * w4.w + b4.w;
  reinterpret_cast<float4*>(out + (size_t)row * 1024)[tid] = r;
}

extern "C" void kernel_launch(void* const* d_in, const int* in_sizes, int n_in,
                              void* d_out, int out_size, void* d_ws, size_t ws_size,
                              hipStream_t stream) {
  const float* qv = (const float*)d_in[0];
  const float* kn = (const float*)d_in[1];
  const int* amask = (const int*)d_in[2];
  const int* ansp = (const int*)d_in[3];
  const float* Wq = (const float*)d_in[4];
  const float* bq = (const float*)d_in[5];
  const float* Wk = (const float*)d_in[6];
  const float* bk = (const float*)d_in[7];
  const float* Wv = (const float*)d_in[8];
  const float* bv = (const float*)d_in[9];
  const float* Wo = (const float*)d_in[10];
  const float* bo = (const float*)d_in[11];
  const float* lnw = (const float*)d_in[12];
  const float* lnb = (const float*)d_in[13];

  char* ws = (char*)d_ws;
  u16* qbf  = (u16*)(ws);
  u16* kbf  = (u16*)(ws + (size_t)(8u << 20));
  u16* pctx0 = qbf;
  u16* pctx1 = kbf;
  float* pl = (float*)(ws + (size_t)(16u << 20));
  u16* ctxm = (u16*)(ws + (size_t)(17u << 20));
  u16* wqT  = (u16*)(ws + (size_t)(24u << 20));
  u16* wkvT = (u16*)(ws + (size_t)(26u << 20));
  u16* woT  = (u16*)(ws + (size_t)(30u << 20));
  u16* Qb   = (u16*)(ws + (size_t)(32u << 20));
  u16* Kb   = (u16*)(ws + (size_t)(40u << 20));
  u16* Vtb  = (u16*)(ws + (size_t)(56u << 20));
  float* oproj = (float*)(ws + (size_t)(32u << 20));

  cvt2_kernel<<<12288, 256, 0, stream>>>(qv, kn, qbf, kbf);
  transpose4_kernel<<<dim3(16, 16, 4), 256, 0, stream>>>(Wq, Wk, Wv, Wo, wqT, wkvT, woT);
  qkv_gemm_kernel<<<1280, 256, 0, stream>>>(qbf, kbf, wqT, wkvT, bq, bk, bv, Qb, Kb, Vtb);
  attn_kernel<<<dim3(32, 16, 2), 256, 0, stream>>>(Qb, Kb, Vtb, ansp, amask, pctx0, pctx1, pl);
  merge_kernel<<<4096, 256, 0, stream>>>(pctx0, pctx1, pl, ctxm);
  o_gemm_kernel<<<dim3(16, 32), 256, 0, stream>>>(ctxm, woT, bo, oproj);
  ln_kernel<<<4096, 256, 0, stream>>>(oproj, qv, lnw, lnb, (float*)d_out);
}